// Round 2
// baseline (301.309 us; speedup 1.0000x reference)
//
#include <hip/hip_runtime.h>
#include <math.h>

// LSTM autoencoder, single timestep, h0=c0=0.
// => whh matrices unused; f-gate unused (f*c0 == 0).
// Fused single cooperative kernel: 7 phases separated by grid barriers.
// 512 blocks x 256 threads = 2048 waves; 2 blocks/CU co-resident.

#define NB 512
#define NT 256

__device__ __forceinline__ float sigmoidf_(float v) {
    return 1.0f / (1.0f + expf(-v));
}

__device__ __forceinline__ float wred(float v) {
    #pragma unroll
    for (int off = 32; off > 0; off >>= 1) v += __shfl_xor(v, off, 64);
    return v;
}

// Grid barrier: one counter per barrier, zeroed by host memset each call.
__device__ __forceinline__ void gbar(unsigned* cnt, unsigned nb) {
    __syncthreads();
    if (threadIdx.x == 0) {
        __threadfence();                       // release: make h writes visible
        atomicAdd(cnt, 1u);                    // device-scope
        while (__hip_atomic_load(cnt, __ATOMIC_RELAXED, __HIP_MEMORY_SCOPE_AGENT) < nb) {
            __builtin_amdgcn_s_sleep(1);
        }
        __threadfence();                       // acquire: invalidate stale caches
    }
    __syncthreads();
}

template<int CLEN>
__device__ __forceinline__ void dot3(const float* __restrict__ wi,
                                     const float* __restrict__ wg,
                                     const float* __restrict__ wo,
                                     const float* __restrict__ x,
                                     int lane, float& si, float& sg, float& so) {
    si = 0.f; sg = 0.f; so = 0.f;
    #pragma unroll 4
    for (int c0 = 0; c0 < CLEN; c0 += 256) {
        const int c = c0 + lane * 4;
        const float4 xv = *reinterpret_cast<const float4*>(x + c);
        const float4 av = *reinterpret_cast<const float4*>(wi + c);
        const float4 gv = *reinterpret_cast<const float4*>(wg + c);
        const float4 ov = *reinterpret_cast<const float4*>(wo + c);
        si += av.x * xv.x + av.y * xv.y + av.z * xv.z + av.w * xv.w;
        sg += gv.x * xv.x + gv.y * xv.y + gv.z * xv.z + gv.w * xv.w;
        so += ov.x * xv.x + ov.y * xv.y + ov.z * xv.z + ov.w * xv.w;
    }
}

__device__ __forceinline__ void epilogue(float si, float sg, float so,
                                         const float* __restrict__ bi,
                                         const float* __restrict__ bh,
                                         int j, int dh, float* __restrict__ h) {
    const float gi = si + bi[j]          + bh[j];
    const float gg = sg + bi[j + 2 * dh] + bh[j + 2 * dh];
    const float go = so + bi[j + 3 * dh] + bh[j + 3 * dh];
    const float cc = sigmoidf_(gi) * tanhf(gg);
    h[j] = sigmoidf_(go) * tanhf(cc);
}

// One row per wave (dh == 2048 == wave count).
template<int C>
__device__ __forceinline__ void cell_full(const float* __restrict__ w,
                                          const float* __restrict__ bi,
                                          const float* __restrict__ bh,
                                          const float* __restrict__ x,
                                          float* __restrict__ h,
                                          int dh, int wv, int lane) {
    const int j = wv;
    const float* wi = w + (size_t)j * C;
    const float* wg = w + ((size_t)j + 2u * (size_t)dh) * C;
    const float* wo = w + ((size_t)j + 3u * (size_t)dh) * C;
    float si, sg, so;
    dot3<C>(wi, wg, wo, x, lane, si, sg, so);
    si = wred(si); sg = wred(sg); so = wred(so);
    if (lane == 0) epilogue(si, sg, so, bi, bh, j, dh, h);
}

// Two waves per row, each half the columns; combine via LDS (dh == 1024).
template<int C>
__device__ __forceinline__ void cell_split2(const float* __restrict__ w,
                                            const float* __restrict__ bi,
                                            const float* __restrict__ bh,
                                            const float* __restrict__ x,
                                            float* __restrict__ h,
                                            int dh, int wv, int lane,
                                            float (*lds)[3]) {
    const int j = wv >> 1;
    const int half = wv & 1;
    const int off = half * (C / 2);
    const float* wi = w + (size_t)j * C + off;
    const float* wg = w + ((size_t)j + 2u * (size_t)dh) * C + off;
    const float* wo = w + ((size_t)j + 3u * (size_t)dh) * C + off;
    float si, sg, so;
    dot3<C / 2>(wi, wg, wo, x + off, lane, si, sg, so);
    si = wred(si); sg = wred(sg); so = wred(so);
    const int wl = threadIdx.x >> 6;
    if (lane == 0) { lds[wl][0] = si; lds[wl][1] = sg; lds[wl][2] = so; }
    __syncthreads();
    if ((wl & 1) == 0 && lane == 0) {
        epilogue(si + lds[wl + 1][0], sg + lds[wl + 1][1], so + lds[wl + 1][2],
                 bi, bh, j, dh, h);
    }
}

// Final linear: 4096 rows, 2 rows per wave, C = 2048.
__device__ __forceinline__ void linear2(const float* __restrict__ w,
                                        const float* __restrict__ b,
                                        const float* __restrict__ x,
                                        float* __restrict__ y,
                                        int wv, int lane) {
    const int j0 = wv, j1 = wv + 2048;
    const float* w0r = w + (size_t)j0 * 2048;
    const float* w1r = w + (size_t)j1 * 2048;
    float s0 = 0.f, s1 = 0.f;
    #pragma unroll 4
    for (int c0 = 0; c0 < 2048; c0 += 256) {
        const int c = c0 + lane * 4;
        const float4 xv = *reinterpret_cast<const float4*>(x + c);
        const float4 a  = *reinterpret_cast<const float4*>(w0r + c);
        const float4 d  = *reinterpret_cast<const float4*>(w1r + c);
        s0 += a.x * xv.x + a.y * xv.y + a.z * xv.z + a.w * xv.w;
        s1 += d.x * xv.x + d.y * xv.y + d.z * xv.z + d.w * xv.w;
    }
    s0 = wred(s0); s1 = wred(s1);
    if (lane == 0) { y[j0] = s0 + b[j0]; y[j1] = s1 + b[j1]; }
}

struct Params {
    const float *x;
    const float *w0, *bi0, *bh0;  // e1l0: R=2048, C=4096
    const float *w1, *bi1, *bh1;  // e1l1: R=2048, C=2048
    const float *w2, *bi2, *bh2;  // e2:   R=1024, C=2048
    const float *w3, *bi3, *bh3;  // d1l0: R=1024, C=1024
    const float *w4, *bi4, *bh4;  // d1l1: R=1024, C=1024
    const float *w5, *bi5, *bh5;  // d2:   R=2048, C=1024
    const float *ow, *ob;         // out:  R=4096, C=2048
    float *out;
    float *ws;
};

__global__ __launch_bounds__(NT, 2) void fused_lstm_ae(Params p) {
    __shared__ float lds[4][3];
    const int lane = threadIdx.x & 63;
    const int wv = (int)((blockIdx.x * NT + threadIdx.x) >> 6);

    unsigned* cnt = (unsigned*)p.ws;   // 16 counters (64 B), zeroed per call
    float* h1 = p.ws + 16;             // 2048
    float* h2 = h1 + 2048;             // 2048
    float* z  = h2 + 2048;             // 1024
    float* h3 = z  + 1024;             // 1024
    float* h4 = h3 + 1024;             // 1024
    float* h5 = h4 + 1024;             // 2048

    cell_full<4096>(p.w0, p.bi0, p.bh0, p.x, h1, 2048, wv, lane);
    gbar(cnt + 0, NB);
    cell_full<2048>(p.w1, p.bi1, p.bh1, h1, h2, 2048, wv, lane);
    gbar(cnt + 1, NB);
    cell_split2<2048>(p.w2, p.bi2, p.bh2, h2, z, 1024, wv, lane, lds);
    gbar(cnt + 2, NB);
    cell_split2<1024>(p.w3, p.bi3, p.bh3, z, h3, 1024, wv, lane, lds);
    gbar(cnt + 3, NB);
    cell_split2<1024>(p.w4, p.bi4, p.bh4, h3, h4, 1024, wv, lane, lds);
    gbar(cnt + 4, NB);
    cell_full<1024>(p.w5, p.bi5, p.bh5, h4, h5, 2048, wv, lane);
    gbar(cnt + 5, NB);
    linear2(p.ow, p.ob, h5, p.out, wv, lane);
}

extern "C" void kernel_launch(void* const* d_in, const int* in_sizes, int n_in,
                              void* d_out, int out_size, void* d_ws, size_t ws_size,
                              hipStream_t stream)
{
    Params p;
    p.x   = (const float*)d_in[0];
    p.w0  = (const float*)d_in[1];
    p.bi0 = (const float*)d_in[3];
    p.bh0 = (const float*)d_in[4];
    p.w1  = (const float*)d_in[5];
    p.bi1 = (const float*)d_in[7];
    p.bh1 = (const float*)d_in[8];
    p.w2  = (const float*)d_in[9];
    p.bi2 = (const float*)d_in[11];
    p.bh2 = (const float*)d_in[12];
    p.w3  = (const float*)d_in[13];
    p.bi3 = (const float*)d_in[15];
    p.bh3 = (const float*)d_in[16];
    p.w4  = (const float*)d_in[17];
    p.bi4 = (const float*)d_in[19];
    p.bh4 = (const float*)d_in[20];
    p.w5  = (const float*)d_in[21];
    p.bi5 = (const float*)d_in[23];
    p.bh5 = (const float*)d_in[24];
    p.ow  = (const float*)d_in[25];
    p.ob  = (const float*)d_in[26];
    p.out = (float*)d_out;
    p.ws  = (float*)d_ws;

    // Zero the barrier counters (must not persist across graph replays).
    hipMemsetAsync(d_ws, 0, 64, stream);

    void* args[] = { &p };
    hipLaunchCooperativeKernel((void*)fused_lstm_ae, dim3(NB), dim3(NT),
                               args, 0, stream);
}

// Round 3
// 151.700 us; speedup vs baseline: 1.9862x; 1.9862x over previous
//
#include <hip/hip_runtime.h>
#include <math.h>

// LSTM autoencoder, single timestep, h0=c0=0.
// => whh matrices unused; f-gate unused (f*c0 == 0).
// Fused cooperative kernel, 7 phases, hierarchical low-contention grid barrier.
// 256 blocks x 512 threads = 2048 waves, 1 block/CU, 8 waves/CU.

#define NB 256
#define NT 512
#define GRPSZ 8
#define NGRP (NB / GRPSZ)               // 32
#define PAD 32                          // u32 per counter line (128 B)
#define PHASE_U32 ((2 * NGRP + 1) * PAD)
#define BAR_U32 16384                   // 64 KB barrier region in ws

__device__ __forceinline__ float sigmoidf_(float v) {
    return 1.0f / (1.0f + expf(-v));
}

__device__ __forceinline__ float wred(float v) {
    #pragma unroll
    for (int off = 32; off > 0; off >>= 1) v += __shfl_xor(v, off, 64);
    return v;
}

__device__ __forceinline__ unsigned aload(const unsigned* p) {
    return __hip_atomic_load(p, __ATOMIC_RELAXED, __HIP_MEMORY_SCOPE_AGENT);
}

// Hierarchical grid barrier: members -> group line; leaders -> central line;
// release via per-group go lines. Padded lines, s_sleep backoff.
__device__ __forceinline__ void gbar(unsigned* base) {
    __syncthreads();
    if (threadIdx.x == 0) {
        __threadfence();                               // release h writes
        const int gid = (int)blockIdx.x / GRPSZ;
        unsigned* garr = base + (size_t)gid * PAD;
        unsigned* ggo  = base + (size_t)(NGRP + gid) * PAD;
        unsigned* cent = base + (size_t)(2 * NGRP) * PAD;
        atomicAdd(garr, 1u);
        if ((blockIdx.x % GRPSZ) == 0) {
            while (aload(garr) < GRPSZ) __builtin_amdgcn_s_sleep(2);
            atomicAdd(cent, 1u);
            if (aload(cent) < NGRP) {
                __builtin_amdgcn_s_sleep(2);
                while (aload(cent) < NGRP) __builtin_amdgcn_s_sleep(16);
            }
            atomicAdd(ggo, 1u);
        } else {
            if (aload(ggo) == 0) {
                __builtin_amdgcn_s_sleep(2);
                while (aload(ggo) == 0) __builtin_amdgcn_s_sleep(16);
            }
        }
        __threadfence();                               // acquire before reads
    }
    __syncthreads();
}

// Stage the input vector for this phase into LDS (fresh post-fence reads).
template<int N>
__device__ __forceinline__ void stage_x(const float* __restrict__ g, float* xs) {
    for (int i = threadIdx.x * 4; i < N; i += NT * 4)
        *reinterpret_cast<float4*>(xs + i) = *reinterpret_cast<const float4*>(g + i);
    __syncthreads();
}

template<int CLEN>
__device__ __forceinline__ void dot3(const float* __restrict__ wi,
                                     const float* __restrict__ wg,
                                     const float* __restrict__ wo,
                                     const float* __restrict__ xs,  // LDS
                                     int lane, float& si, float& sg, float& so) {
    si = 0.f; sg = 0.f; so = 0.f;
    #pragma unroll 4
    for (int c0 = 0; c0 < CLEN; c0 += 256) {
        const int c = c0 + lane * 4;
        const float4 xv = *reinterpret_cast<const float4*>(xs + c);
        const float4 av = *reinterpret_cast<const float4*>(wi + c);
        const float4 gv = *reinterpret_cast<const float4*>(wg + c);
        const float4 ov = *reinterpret_cast<const float4*>(wo + c);
        si += av.x * xv.x + av.y * xv.y + av.z * xv.z + av.w * xv.w;
        sg += gv.x * xv.x + gv.y * xv.y + gv.z * xv.z + gv.w * xv.w;
        so += ov.x * xv.x + ov.y * xv.y + ov.z * xv.z + ov.w * xv.w;
    }
}

__device__ __forceinline__ void epilogue(float si, float sg, float so,
                                         const float* __restrict__ bi,
                                         const float* __restrict__ bh,
                                         int j, int dh, float* __restrict__ h) {
    const float gi = si + bi[j]          + bh[j];
    const float gg = sg + bi[j + 2 * dh] + bh[j + 2 * dh];
    const float go = so + bi[j + 3 * dh] + bh[j + 3 * dh];
    const float cc = sigmoidf_(gi) * tanhf(gg);
    h[j] = sigmoidf_(go) * tanhf(cc);
}

// One row per wave (dh == 2048 == total waves).
template<int C>
__device__ __forceinline__ void cell_full(const float* __restrict__ w,
                                          const float* __restrict__ bi,
                                          const float* __restrict__ bh,
                                          const float* __restrict__ xs,
                                          float* __restrict__ h,
                                          int dh, int wv, int lane) {
    const int j = wv;
    const float* wi = w + (size_t)j * C;
    const float* wg = w + ((size_t)j + 2u * (size_t)dh) * C;
    const float* wo = w + ((size_t)j + 3u * (size_t)dh) * C;
    float si, sg, so;
    dot3<C>(wi, wg, wo, xs, lane, si, sg, so);
    si = wred(si); sg = wred(sg); so = wred(so);
    if (lane == 0) epilogue(si, sg, so, bi, bh, j, dh, h);
}

// Two waves per row, half the columns each; combine via LDS (dh == 1024).
template<int C>
__device__ __forceinline__ void cell_split2(const float* __restrict__ w,
                                            const float* __restrict__ bi,
                                            const float* __restrict__ bh,
                                            const float* __restrict__ xs,
                                            float* __restrict__ h,
                                            int dh, int wv, int wl, int lane,
                                            float (*red)[3]) {
    const int j = wv >> 1;
    const int off = (wv & 1) * (C / 2);
    const float* wi = w + (size_t)j * C + off;
    const float* wg = w + ((size_t)j + 2u * (size_t)dh) * C + off;
    const float* wo = w + ((size_t)j + 3u * (size_t)dh) * C + off;
    float si, sg, so;
    dot3<C / 2>(wi, wg, wo, xs + off, lane, si, sg, so);
    si = wred(si); sg = wred(sg); so = wred(so);
    if (lane == 0) { red[wl][0] = si; red[wl][1] = sg; red[wl][2] = so; }
    __syncthreads();
    if ((wl & 1) == 0 && lane == 0) {
        epilogue(si + red[wl + 1][0], sg + red[wl + 1][1], so + red[wl + 1][2],
                 bi, bh, j, dh, h);
    }
}

// Final linear: 4096 rows, 2 rows per wave, C = 2048.
__device__ __forceinline__ void linear2(const float* __restrict__ w,
                                        const float* __restrict__ b,
                                        const float* __restrict__ xs,
                                        float* __restrict__ y,
                                        int wv, int lane) {
    const int j0 = wv, j1 = wv + 2048;
    const float* w0r = w + (size_t)j0 * 2048;
    const float* w1r = w + (size_t)j1 * 2048;
    float s0 = 0.f, s1 = 0.f;
    #pragma unroll 4
    for (int c0 = 0; c0 < 2048; c0 += 256) {
        const int c = c0 + lane * 4;
        const float4 xv = *reinterpret_cast<const float4*>(xs + c);
        const float4 a  = *reinterpret_cast<const float4*>(w0r + c);
        const float4 d  = *reinterpret_cast<const float4*>(w1r + c);
        s0 += a.x * xv.x + a.y * xv.y + a.z * xv.z + a.w * xv.w;
        s1 += d.x * xv.x + d.y * xv.y + d.z * xv.z + d.w * xv.w;
    }
    s0 = wred(s0); s1 = wred(s1);
    if (lane == 0) { y[j0] = s0 + b[j0]; y[j1] = s1 + b[j1]; }
}

struct Params {
    const float *x;
    const float *w0, *bi0, *bh0;  // e1l0: R=2048, C=4096
    const float *w1, *bi1, *bh1;  // e1l1: R=2048, C=2048
    const float *w2, *bi2, *bh2;  // e2:   R=1024, C=2048
    const float *w3, *bi3, *bh3;  // d1l0: R=1024, C=1024
    const float *w4, *bi4, *bh4;  // d1l1: R=1024, C=1024
    const float *w5, *bi5, *bh5;  // d2:   R=2048, C=1024
    const float *ow, *ob;         // out:  R=4096, C=2048
    float *out;
    float *ws;
};

__global__ __launch_bounds__(NT, 1) void fused_lstm_ae(Params p) {
    __shared__ float xs[4096];
    __shared__ float red[NT / 64][3];
    const int lane = threadIdx.x & 63;
    const int wl = threadIdx.x >> 6;
    const int wv = (int)blockIdx.x * (NT / 64) + wl;

    unsigned* bar = (unsigned*)p.ws;     // 64 KB, zeroed per call
    float* h1 = p.ws + BAR_U32;          // 2048
    float* h2 = h1 + 2048;               // 2048
    float* z  = h2 + 2048;               // 1024
    float* h3 = z  + 1024;               // 1024
    float* h4 = h3 + 1024;               // 1024
    float* h5 = h4 + 1024;               // 2048

    stage_x<4096>(p.x, xs);
    cell_full<4096>(p.w0, p.bi0, p.bh0, xs, h1, 2048, wv, lane);
    gbar(bar + 0 * PHASE_U32);
    stage_x<2048>(h1, xs);
    cell_full<2048>(p.w1, p.bi1, p.bh1, xs, h2, 2048, wv, lane);
    gbar(bar + 1 * PHASE_U32);
    stage_x<2048>(h2, xs);
    cell_split2<2048>(p.w2, p.bi2, p.bh2, xs, z, 1024, wv, wl, lane, red);
    gbar(bar + 2 * PHASE_U32);
    stage_x<1024>(z, xs);
    cell_split2<1024>(p.w3, p.bi3, p.bh3, xs, h3, 1024, wv, wl, lane, red);
    gbar(bar + 3 * PHASE_U32);
    stage_x<1024>(h3, xs);
    cell_split2<1024>(p.w4, p.bi4, p.bh4, xs, h4, 1024, wv, wl, lane, red);
    gbar(bar + 4 * PHASE_U32);
    stage_x<1024>(h4, xs);
    cell_full<1024>(p.w5, p.bi5, p.bh5, xs, h5, 2048, wv, lane);
    gbar(bar + 5 * PHASE_U32);
    stage_x<2048>(h5, xs);
    linear2(p.ow, p.ob, xs, p.out, wv, lane);
}

extern "C" void kernel_launch(void* const* d_in, const int* in_sizes, int n_in,
                              void* d_out, int out_size, void* d_ws, size_t ws_size,
                              hipStream_t stream)
{
    Params p;
    p.x   = (const float*)d_in[0];
    p.w0  = (const float*)d_in[1];
    p.bi0 = (const float*)d_in[3];
    p.bh0 = (const float*)d_in[4];
    p.w1  = (const float*)d_in[5];
    p.bi1 = (const float*)d_in[7];
    p.bh1 = (const float*)d_in[8];
    p.w2  = (const float*)d_in[9];
    p.bi2 = (const float*)d_in[11];
    p.bh2 = (const float*)d_in[12];
    p.w3  = (const float*)d_in[13];
    p.bi3 = (const float*)d_in[15];
    p.bh3 = (const float*)d_in[16];
    p.w4  = (const float*)d_in[17];
    p.bi4 = (const float*)d_in[19];
    p.bh4 = (const float*)d_in[20];
    p.w5  = (const float*)d_in[21];
    p.bi5 = (const float*)d_in[23];
    p.bh5 = (const float*)d_in[24];
    p.ow  = (const float*)d_in[25];
    p.ob  = (const float*)d_in[26];
    p.out = (float*)d_out;
    p.ws  = (float*)d_ws;

    // Zero barrier counters (must not persist across graph replays).
    hipMemsetAsync(d_ws, 0, BAR_U32 * sizeof(unsigned), stream);

    void* args[] = { &p };
    hipLaunchCooperativeKernel((void*)fused_lstm_ae, dim3(NB), dim3(NT),
                               args, 0, stream);
}

// Round 4
// 59.809 us; speedup vs baseline: 5.0379x; 2.5364x over previous
//
#include <hip/hip_runtime.h>
#include <math.h>

// LSTM autoencoder, single timestep, h0=c0=0.
// => whh matrices unused; f-gate unused (f*c0 == 0).
// 7 plain kernels (graph-captured). Every phase runs 1024 blocks x 256 thr
// = 4096 waves (16 waves/CU) via column-splitting each row's dot products;
// partials combined in LDS. Maximizes in-flight HBM loads per CU.

__device__ __forceinline__ float sigmoidf_(float v) {
    return 1.0f / (1.0f + expf(-v));
}

__device__ __forceinline__ float wred(float v) {
    #pragma unroll
    for (int off = 32; off > 0; off >>= 1) v += __shfl_xor(v, off, 64);
    return v;
}

template<int CLEN>
__device__ __forceinline__ void dot3(const float* __restrict__ wi,
                                     const float* __restrict__ wg,
                                     const float* __restrict__ wo,
                                     const float* __restrict__ x,
                                     int lane, float& si, float& sg, float& so) {
    si = 0.f; sg = 0.f; so = 0.f;
    #pragma unroll 4
    for (int c0 = 0; c0 < CLEN; c0 += 256) {
        const int c = c0 + lane * 4;
        const float4 xv = *reinterpret_cast<const float4*>(x + c);
        const float4 av = *reinterpret_cast<const float4*>(wi + c);
        const float4 gv = *reinterpret_cast<const float4*>(wg + c);
        const float4 ov = *reinterpret_cast<const float4*>(wo + c);
        si += av.x * xv.x + av.y * xv.y + av.z * xv.z + av.w * xv.w;
        sg += gv.x * xv.x + gv.y * xv.y + gv.z * xv.z + gv.w * xv.w;
        so += ov.x * xv.x + ov.y * xv.y + ov.z * xv.z + ov.w * xv.w;
    }
}

__device__ __forceinline__ void epilogue(float si, float sg, float so,
                                         const float* __restrict__ bi,
                                         const float* __restrict__ bh,
                                         int j, int dh, float* __restrict__ h) {
    const float gi = si + bi[j]          + bh[j];
    const float gg = sg + bi[j + 2 * dh] + bh[j + 2 * dh];
    const float go = so + bi[j + 3 * dh] + bh[j + 3 * dh];
    const float cc = sigmoidf_(gi) * tanhf(gg);
    h[j] = sigmoidf_(go) * tanhf(cc);
}

// Block = 4 waves. SPLIT waves cooperate on one row (column split);
// 4/SPLIT rows per block. Grid must be R*SPLIT/4 blocks.
template<int C, int SPLIT>
__global__ __launch_bounds__(256, 4)
void lstm_cell_k(const float* __restrict__ w,
                 const float* __restrict__ bi,
                 const float* __restrict__ bh,
                 const float* __restrict__ x,
                 float* __restrict__ h,
                 int dh)
{
    __shared__ float red[4][3];
    const int lane = threadIdx.x & 63;
    const int wl = threadIdx.x >> 6;
    const int j = (int)blockIdx.x * (4 / SPLIT) + wl / SPLIT;
    const int part = wl % SPLIT;
    constexpr int CL = C / SPLIT;
    const int off = part * CL;

    const float* wi = w + (size_t)j * C + off;
    const float* wg = w + ((size_t)j + 2u * (size_t)dh) * C + off;
    const float* wo = w + ((size_t)j + 3u * (size_t)dh) * C + off;

    float si, sg, so;
    dot3<CL>(wi, wg, wo, x + off, lane, si, sg, so);
    si = wred(si); sg = wred(sg); so = wred(so);

    if (SPLIT > 1) {
        if (lane == 0) { red[wl][0] = si; red[wl][1] = sg; red[wl][2] = so; }
        __syncthreads();
        if (part == 0 && lane == 0) {
            #pragma unroll
            for (int k = 1; k < SPLIT; ++k) {
                si += red[wl + k][0];
                sg += red[wl + k][1];
                so += red[wl + k][2];
            }
            epilogue(si, sg, so, bi, bh, j, dh, h);
        }
    } else {
        if (lane == 0) epilogue(si, sg, so, bi, bh, j, dh, h);
    }
}

// y = W@x + b. One wave per row, 4 rows per block. Grid = R/4.
template<int C>
__global__ __launch_bounds__(256, 4)
void linear_k(const float* __restrict__ w,
              const float* __restrict__ b,
              const float* __restrict__ x,
              float* __restrict__ y)
{
    const int lane = threadIdx.x & 63;
    const int j = (int)blockIdx.x * 4 + (threadIdx.x >> 6);
    const float* wr = w + (size_t)j * C;
    float s = 0.f;
    #pragma unroll 4
    for (int c0 = 0; c0 < C; c0 += 256) {
        const int c = c0 + lane * 4;
        const float4 xv = *reinterpret_cast<const float4*>(x + c);
        const float4 wv = *reinterpret_cast<const float4*>(wr + c);
        s += wv.x * xv.x + wv.y * xv.y + wv.z * xv.z + wv.w * xv.w;
    }
    s = wred(s);
    if (lane == 0) y[j] = s + b[j];
}

extern "C" void kernel_launch(void* const* d_in, const int* in_sizes, int n_in,
                              void* d_out, int out_size, void* d_ws, size_t ws_size,
                              hipStream_t stream)
{
    const float* x        = (const float*)d_in[0];
    const float* e1l0_wih = (const float*)d_in[1];
    const float* e1l0_bih = (const float*)d_in[3];
    const float* e1l0_bhh = (const float*)d_in[4];
    const float* e1l1_wih = (const float*)d_in[5];
    const float* e1l1_bih = (const float*)d_in[7];
    const float* e1l1_bhh = (const float*)d_in[8];
    const float* e2_wih   = (const float*)d_in[9];
    const float* e2_bih   = (const float*)d_in[11];
    const float* e2_bhh   = (const float*)d_in[12];
    const float* d1l0_wih = (const float*)d_in[13];
    const float* d1l0_bih = (const float*)d_in[15];
    const float* d1l0_bhh = (const float*)d_in[16];
    const float* d1l1_wih = (const float*)d_in[17];
    const float* d1l1_bih = (const float*)d_in[19];
    const float* d1l1_bhh = (const float*)d_in[20];
    const float* d2_wih   = (const float*)d_in[21];
    const float* d2_bih   = (const float*)d_in[23];
    const float* d2_bhh   = (const float*)d_in[24];
    const float* out_w    = (const float*)d_in[25];
    const float* out_b    = (const float*)d_in[26];
    float* out = (float*)d_out;

    float* ws = (float*)d_ws;
    float* h1 = ws;           // 2048
    float* h2 = ws + 2048;    // 2048
    float* z  = ws + 4096;    // 1024
    float* h3 = ws + 5120;    // 1024
    float* h4 = ws + 6144;    // 1024
    float* h5 = ws + 7168;    // 2048

    // Encoder
    lstm_cell_k<4096, 2><<<1024, 256, 0, stream>>>(e1l0_wih, e1l0_bih, e1l0_bhh, x,  h1, 2048);
    lstm_cell_k<2048, 2><<<1024, 256, 0, stream>>>(e1l1_wih, e1l1_bih, e1l1_bhh, h1, h2, 2048);
    lstm_cell_k<2048, 4><<<1024, 256, 0, stream>>>(e2_wih,   e2_bih,   e2_bhh,   h2, z,  1024);
    // Decoder
    lstm_cell_k<1024, 4><<<1024, 256, 0, stream>>>(d1l0_wih, d1l0_bih, d1l0_bhh, z,  h3, 1024);
    lstm_cell_k<1024, 4><<<1024, 256, 0, stream>>>(d1l1_wih, d1l1_bih, d1l1_bhh, h3, h4, 1024);
    lstm_cell_k<1024, 2><<<1024, 256, 0, stream>>>(d2_wih,   d2_bih,   d2_bhh,   h4, h5, 2048);
    // Output projection
    linear_k<2048><<<1024, 256, 0, stream>>>(out_w, out_b, h5, out);
}

// Round 5
// 58.398 us; speedup vs baseline: 5.1596x; 1.0242x over previous
//
#include <hip/hip_runtime.h>
#include <math.h>

// LSTM autoencoder, single timestep, h0=c0=0.
// => whh matrices unused; f-gate unused (f*c0 == 0).
// 7 plain kernels (graph-captured). 512-thread blocks (8 waves); every row's
// dot product is column-split across SPLIT waves (LDS combine) so each phase
// launches up to 8192 waves (32 waves/CU) for maximum loads-in-flight.

__device__ __forceinline__ float sigmoidf_(float v) {
    return 1.0f / (1.0f + expf(-v));
}

__device__ __forceinline__ float wred(float v) {
    #pragma unroll
    for (int off = 32; off > 0; off >>= 1) v += __shfl_xor(v, off, 64);
    return v;
}

// CLEN must be a multiple of 256.
template<int CLEN>
__device__ __forceinline__ void dot3(const float* __restrict__ wi,
                                     const float* __restrict__ wg,
                                     const float* __restrict__ wo,
                                     const float* __restrict__ x,
                                     int lane, float& si, float& sg, float& so) {
    si = 0.f; sg = 0.f; so = 0.f;
    #pragma unroll 4
    for (int c0 = 0; c0 < CLEN; c0 += 256) {
        const int c = c0 + lane * 4;
        const float4 xv = *reinterpret_cast<const float4*>(x + c);
        const float4 av = *reinterpret_cast<const float4*>(wi + c);
        const float4 gv = *reinterpret_cast<const float4*>(wg + c);
        const float4 ov = *reinterpret_cast<const float4*>(wo + c);
        si += av.x * xv.x + av.y * xv.y + av.z * xv.z + av.w * xv.w;
        sg += gv.x * xv.x + gv.y * xv.y + gv.z * xv.z + gv.w * xv.w;
        so += ov.x * xv.x + ov.y * xv.y + ov.z * xv.z + ov.w * xv.w;
    }
}

__device__ __forceinline__ void epilogue(float si, float sg, float so,
                                         const float* __restrict__ bi,
                                         const float* __restrict__ bh,
                                         int j, int dh, float* __restrict__ h) {
    const float gi = si + bi[j]          + bh[j];
    const float gg = sg + bi[j + 2 * dh] + bh[j + 2 * dh];
    const float go = so + bi[j + 3 * dh] + bh[j + 3 * dh];
    const float cc = sigmoidf_(gi) * tanhf(gg);
    h[j] = sigmoidf_(go) * tanhf(cc);
}

// Block = 8 waves (512 threads). SPLIT waves cooperate on one row (column
// split, LDS combine); 8/SPLIT rows per block. Grid = R*SPLIT/8 blocks.
template<int C, int SPLIT>
__global__ __launch_bounds__(512)
void lstm_cell_k(const float* __restrict__ w,
                 const float* __restrict__ bi,
                 const float* __restrict__ bh,
                 const float* __restrict__ x,
                 float* __restrict__ h,
                 int dh)
{
    __shared__ float red[8][3];
    const int lane = threadIdx.x & 63;
    const int wl = threadIdx.x >> 6;
    const int j = (int)blockIdx.x * (8 / SPLIT) + wl / SPLIT;
    const int part = wl % SPLIT;
    constexpr int CL = C / SPLIT;
    const int off = part * CL;

    const float* wi = w + (size_t)j * C + off;
    const float* wg = w + ((size_t)j + 2u * (size_t)dh) * C + off;
    const float* wo = w + ((size_t)j + 3u * (size_t)dh) * C + off;

    float si, sg, so;
    dot3<CL>(wi, wg, wo, x + off, lane, si, sg, so);
    si = wred(si); sg = wred(sg); so = wred(so);

    if (SPLIT > 1) {
        if (lane == 0) { red[wl][0] = si; red[wl][1] = sg; red[wl][2] = so; }
        __syncthreads();
        if (part == 0 && lane == 0) {
            #pragma unroll
            for (int k = 1; k < SPLIT; ++k) {
                si += red[wl + k][0];
                sg += red[wl + k][1];
                so += red[wl + k][2];
            }
            epilogue(si, sg, so, bi, bh, j, dh, h);
        }
    } else {
        if (lane == 0) epilogue(si, sg, so, bi, bh, j, dh, h);
    }
}

// y = W@x + b. SPLIT waves per row, 8/SPLIT rows per block. Grid = R*SPLIT/8.
template<int C, int SPLIT>
__global__ __launch_bounds__(512)
void linear_k(const float* __restrict__ w,
              const float* __restrict__ b,
              const float* __restrict__ x,
              float* __restrict__ y)
{
    __shared__ float red[8];
    const int lane = threadIdx.x & 63;
    const int wl = threadIdx.x >> 6;
    const int j = (int)blockIdx.x * (8 / SPLIT) + wl / SPLIT;
    const int part = wl % SPLIT;
    constexpr int CL = C / SPLIT;
    const int off = part * CL;

    const float* wr = w + (size_t)j * C + off;
    const float* xo = x + off;
    float s = 0.f;
    #pragma unroll 4
    for (int c0 = 0; c0 < CL; c0 += 256) {
        const int c = c0 + lane * 4;
        const float4 xv = *reinterpret_cast<const float4*>(xo + c);
        const float4 wv = *reinterpret_cast<const float4*>(wr + c);
        s += wv.x * xv.x + wv.y * xv.y + wv.z * xv.z + wv.w * xv.w;
    }
    s = wred(s);
    if (SPLIT > 1) {
        if (lane == 0) red[wl] = s;
        __syncthreads();
        if (part == 0 && lane == 0) {
            #pragma unroll
            for (int k = 1; k < SPLIT; ++k) s += red[wl + k];
            y[j] = s + b[j];
        }
    } else {
        if (lane == 0) y[j] = s + b[j];
    }
}

extern "C" void kernel_launch(void* const* d_in, const int* in_sizes, int n_in,
                              void* d_out, int out_size, void* d_ws, size_t ws_size,
                              hipStream_t stream)
{
    const float* x        = (const float*)d_in[0];
    const float* e1l0_wih = (const float*)d_in[1];
    const float* e1l0_bih = (const float*)d_in[3];
    const float* e1l0_bhh = (const float*)d_in[4];
    const float* e1l1_wih = (const float*)d_in[5];
    const float* e1l1_bih = (const float*)d_in[7];
    const float* e1l1_bhh = (const float*)d_in[8];
    const float* e2_wih   = (const float*)d_in[9];
    const float* e2_bih   = (const float*)d_in[11];
    const float* e2_bhh   = (const float*)d_in[12];
    const float* d1l0_wih = (const float*)d_in[13];
    const float* d1l0_bih = (const float*)d_in[15];
    const float* d1l0_bhh = (const float*)d_in[16];
    const float* d1l1_wih = (const float*)d_in[17];
    const float* d1l1_bih = (const float*)d_in[19];
    const float* d1l1_bhh = (const float*)d_in[20];
    const float* d2_wih   = (const float*)d_in[21];
    const float* d2_bih   = (const float*)d_in[23];
    const float* d2_bhh   = (const float*)d_in[24];
    const float* out_w    = (const float*)d_in[25];
    const float* out_b    = (const float*)d_in[26];
    float* out = (float*)d_out;

    float* ws = (float*)d_ws;
    float* h1 = ws;           // 2048
    float* h2 = ws + 2048;    // 2048
    float* z  = ws + 4096;    // 1024
    float* h3 = ws + 5120;    // 1024
    float* h4 = ws + 6144;    // 1024
    float* h5 = ws + 7168;    // 2048

    // Encoder: grids = R*SPLIT/8
    lstm_cell_k<4096, 4><<<1024, 512, 0, stream>>>(e1l0_wih, e1l0_bih, e1l0_bhh, x,  h1, 2048);
    lstm_cell_k<2048, 4><<<1024, 512, 0, stream>>>(e1l1_wih, e1l1_bih, e1l1_bhh, h1, h2, 2048);
    lstm_cell_k<2048, 8><<<1024, 512, 0, stream>>>(e2_wih,   e2_bih,   e2_bhh,   h2, z,  1024);
    // Decoder
    lstm_cell_k<1024, 4><<< 512, 512, 0, stream>>>(d1l0_wih, d1l0_bih, d1l0_bhh, z,  h3, 1024);
    lstm_cell_k<1024, 4><<< 512, 512, 0, stream>>>(d1l1_wih, d1l1_bih, d1l1_bhh, h3, h4, 1024);
    lstm_cell_k<1024, 4><<<1024, 512, 0, stream>>>(d2_wih,   d2_bih,   d2_bhh,   h4, h5, 2048);
    // Output projection
    linear_k<2048, 2><<<1024, 512, 0, stream>>>(out_w, out_b, h5, out);
}